// Round 14
// baseline (150.517 us; speedup 1.0000x reference)
//
#include <hip/hip_runtime.h>
#include <cstdint>
#include <math.h>

#define N_     8192
#define D_     256
#define NLBL   128
#define TEMP_INV 14.285714285714286f
#define HARDK  10
#define THETA  0.16f
#define GCAP   256              // per-label list capacity (mean 64, max ~104)

#define NCHUNK 32
#define CHUNK  (N_ / NCHUNK)    // 256 cols per block
#define TILES  (CHUNK / 32)     // 8
#define CSLOT  16               // per-(row,chunk): slots 0-7 = kg0, 8-15 = kg1

typedef __attribute__((ext_vector_type(8)))  short bf16x8;
typedef __attribute__((ext_vector_type(16))) float f32x16;

// ---------------- Threefry-2x32, key=(0,42): exact-match validated R1-R13 ----------------
__device__ __forceinline__ uint32_t rotl32(uint32_t x, int n) {
  return (x << n) | (x >> (32 - n));
}
__device__ uint32_t tf_bits(uint32_t idx) {
  uint32_t x0 = 0u, x1 = idx;
  const uint32_t k0 = 0u, k1 = 42u;
  const uint32_t k2 = k0 ^ k1 ^ 0x1BD11BDAu;
  x0 += k0; x1 += k1;
#define TFR(r) { x0 += x1; x1 = rotl32(x1, r); x1 ^= x0; }
  TFR(13) TFR(15) TFR(26) TFR(6)
  x0 += k1; x1 += k2 + 1u;
  TFR(17) TFR(29) TFR(16) TFR(24)
  x0 += k2; x1 += k0 + 2u;
  TFR(13) TFR(15) TFR(26) TFR(6)
  x0 += k0; x1 += k1 + 3u;
  TFR(17) TFR(29) TFR(16) TFR(24)
  x0 += k1; x1 += k2 + 4u;
  TFR(13) TFR(15) TFR(26) TFR(6)
  x0 += k2; x1 += k0 + 5u;
#undef TFR
  return x0 ^ x1;
}

__device__ __forceinline__ uint32_t f2bf(float x) {  // RNE
  uint32_t b = __float_as_uint(x);
  return (b + 0x7FFFu + ((b >> 16) & 1u)) >> 16;
}

// ---------------- K1: fused prep (norm + bf16 + transpose to zt) AND group masks --------
__global__ __launch_bounds__(256) void prep_group_kernel(
    const float* __restrict__ feats, const int* __restrict__ labels,
    float* __restrict__ inv_norm, unsigned short* __restrict__ zt,
    uint32_t* __restrict__ mask_g, int* __restrict__ glist, int* __restrict__ cnt_g) {
  __shared__ uint4 tile[64][33];   // bf16 rows staged for transpose (+pad)
  __shared__ int lcnt;
  const int tid = threadIdx.x;

  if (blockIdx.x < 128) {
    const int row0 = blockIdx.x * 64;
    const int wv = tid >> 6, l = tid & 63;
#pragma unroll 4
    for (int rr = 0; rr < 16; ++rr) {
      const int rloc = wv * 16 + rr;
      const int row = row0 + rloc;
      float4 v = ((const float4*)feats)[(size_t)row * 64 + l];
      float ss = v.x * v.x + v.y * v.y + v.z * v.z + v.w * v.w;
#pragma unroll
      for (int o = 32; o; o >>= 1) ss += __shfl_xor(ss, o);
      float inv = 1.0f / fmaxf(sqrtf(ss), 1e-12f);
      if (l == 0) inv_norm[row] = inv;
      uint2 p;
      p.x = f2bf(v.x * inv) | (f2bf(v.y * inv) << 16);
      p.y = f2bf(v.z * inv) | (f2bf(v.w * inv) << 16);
      *(uint2*)((char*)&tile[0][0] + rloc * 528 + l * 8) = p;
    }
    __syncthreads();
#pragma unroll
    for (int it = 0; it < 8; ++it) {
      int c = it * 4 + (tid >> 6);
      int r = tid & 63;                  // consecutive r -> contiguous 1KB store
      ((uint4*)zt)[(size_t)c * N_ + row0 + r] = tile[r][c];
    }
  } else {
    const int b = blockIdx.x - 128;
    const int lane = tid & 63, wv = tid >> 6;
    if (tid == 0) lcnt = 0;
    __syncthreads();
    for (int it = 0; it < N_; it += 256) {
      int col = it + tid;
      bool pred = (labels[col] == b);
      unsigned long long m = __ballot(pred);
      if (lane == 0) {
        int w0 = (it + wv * 64) >> 5;
        mask_g[b * 256 + w0]     = (uint32_t)m;
        mask_g[b * 256 + w0 + 1] = (uint32_t)(m >> 32);
      }
      if (pred) {
        int p = atomicAdd(&lcnt, 1);
        if (p < GCAP) glist[b * GCAP + p] = col;
      }
    }
    __syncthreads();
    if (tid == 0) cnt_g[b] = lcnt;
  }
}

// ---------------- K2: 1-wave blocks, wave-private dbuf staging, ZERO barriers ----------
__device__ __forceinline__ void stage16(const unsigned short* zt, char (*AbK)[1024],
                                        int colT, int l, int kg) {
  // plane (kk*2+kg), rows colT..colT+31 contiguous per 32-lane half
  const char* base = (const char*)zt + ((size_t)kg * N_ + colT + (l & 31)) * 16;
#pragma unroll
  for (int kk = 0; kk < 16; ++kk) {
    __builtin_amdgcn_global_load_lds(
        (const __attribute__((address_space(1))) void*)(base + (size_t)kk * (2 * N_ * 16)),
        (__attribute__((address_space(3))) void*)(&AbK[kk][0]), 16, 0, 0);
  }
}

#define INS8(H0,H1,H2,H3,H4,H5,H6,H7,POS,C) \
  { H0 = (POS==0)?(C):H0; H1 = (POS==1)?(C):H1; H2 = (POS==2)?(C):H2; H3 = (POS==3)?(C):H3; \
    H4 = (POS==4)?(C):H4; H5 = (POS==5)?(C):H5; H6 = (POS==6)?(C):H6; H7 = (POS==7)?(C):H7; \
    ++POS; }

__global__ __launch_bounds__(64) void collect_kernel(const unsigned short* __restrict__ zt,
                                                     const int* __restrict__ labels,
                                                     const uint32_t* __restrict__ mask_g,
                                                     float* __restrict__ vals,
                                                     int* __restrict__ counts) {
  __shared__ char Ab[2][16][1024];        // wave-private double buffer, 32 KB

  const int l = threadIdx.x & 63;
  const int kg = l >> 5;
  const int bx = blockIdx.x;
  const int rc = bx & 127, cc = bx >> 7;
  const int col0 = cc * CHUNK;
  const int rowA = rc * 64 + (l & 31);   // rowgroup A
  const int rowB = rowA + 32;            // rowgroup B
  const int labA = labels[rowA];
  const int labB = labels[rowB];

  // all 8 tile-masks preloaded to registers
  uint32_t mA[TILES], mB[TILES];
  {
    const uint4* ma = (const uint4*)(mask_g + labA * 256 + (col0 >> 5));
    const uint4* mb = (const uint4*)(mask_g + labB * 256 + (col0 >> 5));
    uint4 a0 = ma[0], a1 = ma[1], b0 = mb[0], b1 = mb[1];
    mA[0]=a0.x; mA[1]=a0.y; mA[2]=a0.z; mA[3]=a0.w;
    mA[4]=a1.x; mA[5]=a1.y; mA[6]=a1.z; mA[7]=a1.w;
    mB[0]=b0.x; mB[1]=b0.y; mB[2]=b0.z; mB[3]=b0.w;
    mB[4]=b1.x; mB[5]=b1.y; mB[6]=b1.z; mB[7]=b1.w;
  }

  // B fragments from K-major planes (contiguous 512B per 32-lane half)
  bf16x8 bfA[16], bfB[16];
  {
    const uint4* ztq = (const uint4*)zt;
#pragma unroll
    for (int kk = 0; kk < 16; ++kk) {
      bfA[kk] = *(const bf16x8*)&ztq[(size_t)(kk * 2 + kg) * N_ + rowA];
      bfB[kk] = *(const bf16x8*)&ztq[(size_t)(kk * 2 + kg) * N_ + rowB];
    }
  }

  // hit slots in registers (static select-chain)
  float hA0=0,hA1=0,hA2=0,hA3=0,hA4=0,hA5=0,hA6=0,hA7=0;
  float hB0=0,hB1=0,hB2=0,hB3=0,hB4=0,hB5=0,hB6=0,hB7=0;
  int posA = 0, posB = 0;

  // prologue: 2-deep wave-private prefetch. In-order VMEM returns: vmcnt(16)
  // => all loads older than the last 16 (tile1's stage) are done => tile0 landed.
  stage16(zt, Ab[0], col0 + 0 * 32, l, kg);
  stage16(zt, Ab[1], col0 + 1 * 32, l, kg);
  asm volatile("s_waitcnt vmcnt(16)" ::: "memory");
  __builtin_amdgcn_sched_barrier(0);

#pragma unroll
  for (int t = 0; t < TILES; ++t) {
    f32x16 accA, accB;
#pragma unroll
    for (int r = 0; r < 16; ++r) { accA[r] = 0.f; accB[r] = 0.f; }
    __builtin_amdgcn_s_setprio(1);
#pragma unroll
    for (int kk = 0; kk < 16; ++kk) {
      bf16x8 a = *(const bf16x8*)&Ab[t & 1][kk][l * 16];   // one LDS read feeds 2 MFMAs
      accA = __builtin_amdgcn_mfma_f32_32x32x16_bf16(a, bfA[kk], accA, 0, 0, 0);
      accB = __builtin_amdgcn_mfma_f32_32x32x16_bf16(a, bfB[kk], accB, 0, 0, 0);
    }
    __builtin_amdgcn_s_setprio(0);

    // re-stage this buffer for tile t+2 (reads of it completed above via lgkm waits)
    if (t + 2 < TILES) stage16(zt, Ab[t & 1], col0 + (t + 2) * 32, l, kg);

    // scan both rowgroups into register slots (__any-gated: fires ~29%/step)
    const uint32_t wshA = mA[t] >> (kg * 4);
    const uint32_t wshB = mB[t] >> (kg * 4);
#pragma unroll
    for (int r = 0; r < 16; ++r) {
      const int cpos = (r & 3) + 8 * (r >> 2);
      bool hitA = ((((wshA >> cpos) & 1u) == 0u) && (accA[r] > THETA));
      if (__any(hitA)) {
        if (hitA) { INS8(hA0,hA1,hA2,hA3,hA4,hA5,hA6,hA7, posA, accA[r]); }
      }
      bool hitB = ((((wshB >> cpos) & 1u) == 0u) && (accB[r] > THETA));
      if (__any(hitB)) {
        if (hitB) { INS8(hB0,hB1,hB2,hB3,hB4,hB5,hB6,hB7, posB, accB[r]); }
      }
    }

    // counted wait: 16 loads (stage t+2) issued after stage(t+1) => vmcnt(16)
    // guarantees tile t+1 landed, stage(t+2) stays in flight. No barriers.
    if (t < TILES - 2) {
      asm volatile("s_waitcnt vmcnt(16)" ::: "memory");
      __builtin_amdgcn_sched_barrier(0);
    } else if (t == TILES - 2) {
      asm volatile("s_waitcnt vmcnt(0)" ::: "memory");
      __builtin_amdgcn_sched_barrier(0);
    }
  }

  // ---- flush: registers -> global (coalesced float4 stores) ----
  {
    float4 a0 = {hA0, hA1, hA2, hA3};
    float4 a1 = {hA4, hA5, hA6, hA7};
    float4 b0 = {hB0, hB1, hB2, hB3};
    float4 b1 = {hB4, hB5, hB6, hB7};
    float* dA = vals + ((size_t)rowA * NCHUNK + cc) * CSLOT + kg * 8;
    float* dB = vals + ((size_t)rowB * NCHUNK + cc) * CSLOT + kg * 8;
    *(float4*)(dA)     = a0;
    *(float4*)(dA + 4) = a1;
    *(float4*)(dB)     = b0;
    *(float4*)(dB + 4) = b1;
    counts[(rowA * NCHUNK + cc) * 2 + kg] = posA;
    counts[(rowB * NCHUNK + cc) * 2 + kg] = posB;
  }
}

// ---------------- K3: finalize (1 wave/row): pos pick + top-10 of collected + loss ----------------
__global__ __launch_bounds__(256) void finalize_kernel(
    const float* __restrict__ feats, const int* __restrict__ labels,
    const float* __restrict__ inv_norm,
    const int* __restrict__ glist, const int* __restrict__ cnt_g,
    const int* __restrict__ counts, const float* __restrict__ vals,
    float* __restrict__ li, int* __restrict__ valid) {
  const int row = blockIdx.x * 4 + (threadIdx.x >> 6);
  const int lane = threadIdx.x & 63;
  const int lab = labels[row];
  const int gc = cnt_g[lab];
  const int gn = gc < GCAP ? gc : GCAP;
  const float4* feats4 = (const float4*)feats;

  // --- positive pick: threefry argmax over same-label (excl self) ---
  uint32_t bk = 0u; int bj = -1;
  for (int e = lane; e < gn; e += 64) {
    int j = glist[lab * GCAP + e];
    if (j != row) {
      uint32_t key = tf_bits((uint32_t)row * (uint32_t)N_ + (uint32_t)j) >> 9;
      if (bj < 0 || key > bk || (key == bk && j < bj)) { bk = key; bj = j; }
    }
  }
#pragma unroll
  for (int o = 32; o; o >>= 1) {
    uint32_t ok = __shfl_xor(bk, o);
    int oj = __shfl_xor(bj, o);
    if (oj >= 0 && (bj < 0 || ok > bk || (ok == bk && oj < bj))) { bk = ok; bj = oj; }
  }

  // --- exact fp32 positive cosine ---
  float pc = 0.f;
  if (bj >= 0) {
    float4 a = feats4[(size_t)row * 64 + lane];
    float4 b = feats4[(size_t)bj * 64 + lane];
    float p = a.x * b.x + a.y * b.y + a.z * b.z + a.w * b.w;
#pragma unroll
    for (int o = 32; o; o >>= 1) p += __shfl_xor(p, o);
    pc = p * inv_norm[row] * inv_norm[bj];
  }

  // --- load collected: 32 cells x 16 slots = 512, 8 per lane (coalesced) ---
  float vv[8];
  int ovf = 0;
#pragma unroll
  for (int q = 0; q < 8; ++q) {
    int s = lane + 64 * q;           // slot id 0..511
    int cell = s >> 4, wi = s & 15;  // chunk cell 0..31; slot 0-7=kg0, 8-15=kg1
    int c0 = counts[(row * NCHUNK + cell) * 2 + 0];
    int c1 = counts[(row * NCHUNK + cell) * 2 + 1];
    ovf |= ((c0 > 8) || (c1 > 8)) ? 1 : 0;
    float val = vals[(size_t)row * (NCHUNK * CSLOT) + s];
    bool live = (wi < 8) ? (wi < c0) : ((wi - 8) < c1);
    vv[q] = live ? val : -INFINITY;
  }

  float num = expf(pc * TEMP_INV);
  float den = num;
  int got = 0;
#pragma unroll 1
  for (int it = 0; it < HARDK; ++it) {
    float lm = fmaxf(fmaxf(fmaxf(vv[0], vv[1]), fmaxf(vv[2], vv[3])),
                     fmaxf(fmaxf(vv[4], vv[5]), fmaxf(vv[6], vv[7])));
    float wm = lm;
#pragma unroll
    for (int o = 32; o; o >>= 1) wm = fmaxf(wm, __shfl_xor(wm, o));
    if (wm < -1e37f) break;
    den += expf(wm * TEMP_INV);
    ++got;
    unsigned long long b = __ballot(lm == wm);
    int fl = __ffsll((long long)b) - 1;
    if (lane == fl) {
      if      (vv[0] == wm) vv[0] = -INFINITY;
      else if (vv[1] == wm) vv[1] = -INFINITY;
      else if (vv[2] == wm) vv[2] = -INFINITY;
      else if (vv[3] == wm) vv[3] = -INFINITY;
      else if (vv[4] == wm) vv[4] = -INFINITY;
      else if (vv[5] == wm) vv[5] = -INFINITY;
      else if (vv[6] == wm) vv[6] = -INFINITY;
      else                  vv[7] = -INFINITY;
    }
  }

  const int ndiff = N_ - gc;
  const bool vld = (bj >= 0) && (ndiff > 0);
  const int want = ndiff < HARDK ? ndiff : HARDK;

  // --- exact cooperative fallback (P ~ 1e-9/cell; guarantees exactness) ---
  if (vld && (__any(ovf) || got < want)) {
    float tk[HARDK];
#pragma unroll
    for (int k = 0; k < HARDK; ++k) tk[k] = -INFINITY;
    const float invr = inv_norm[row];
    const float4 a = feats4[(size_t)row * 64 + lane];   // whole row: 64 lanes x float4
#pragma unroll 1
    for (int j = 0; j < N_; ++j) {
      if (j == row || labels[j] == lab) continue;       // wave-uniform branch
      float4 b = feats4[(size_t)j * 64 + lane];
      float p = a.x * b.x + a.y * b.y + a.z * b.z + a.w * b.w;
#pragma unroll
      for (int o = 32; o; o >>= 1) p += __shfl_xor(p, o);
      float c = p * invr * inv_norm[j];                 // wave-uniform value
      if (c > tk[0]) {
        tk[0] = c;
#pragma unroll
        for (int q = 0; q < HARDK - 1; ++q)
          if (tk[q] > tk[q + 1]) { float tmp = tk[q]; tk[q] = tk[q + 1]; tk[q + 1] = tmp; }
      }
    }
    den = num;
#pragma unroll
    for (int k = 0; k < HARDK; ++k)
      if (tk[k] > -1e37f) den += expf(tk[k] * TEMP_INV);
  }

  float L = 0.f;
  if (vld) L = -logf(fmaxf(num / fmaxf(den, 1e-8f), 1e-8f));
  if (lane == 0) {
    li[row] = L;
    valid[row] = vld ? 1 : 0;
  }
}

// ---------------- K4: final mean ----------------
__global__ __launch_bounds__(256) void reduce_kernel(const float* __restrict__ li,
                                                     const int* __restrict__ valid,
                                                     float* __restrict__ out) {
  __shared__ float ssum[4];
  __shared__ int scnt[4];
  float s = 0.f; int c = 0;
  for (int i = threadIdx.x; i < N_; i += 256) { s += li[i]; c += valid[i]; }
#pragma unroll
  for (int o = 32; o; o >>= 1) { s += __shfl_down(s, o); c += __shfl_down(c, o); }
  if ((threadIdx.x & 63) == 0) { ssum[threadIdx.x >> 6] = s; scnt[threadIdx.x >> 6] = c; }
  __syncthreads();
  if (threadIdx.x == 0) {
    float S = 0.f; int C = 0;
    for (int w = 0; w < 4; ++w) { S += ssum[w]; C += scnt[w]; }
    out[0] = S / (float)(C > 0 ? C : 1);
  }
}

extern "C" void kernel_launch(void* const* d_in, const int* in_sizes, int n_in,
                              void* d_out, int out_size, void* d_ws, size_t ws_size,
                              hipStream_t stream) {
  const float* feats  = (const float*)d_in[0];
  const int*   labels = (const int*)d_in[1];
  float* out = (float*)d_out;

  char* w = (char*)d_ws;
  unsigned short* zt  = (unsigned short*)w;  w += (size_t)N_ * D_ * 2;        // 4 MB (K-major)
  float* inv_norm = (float*)w;               w += (size_t)N_ * 4;
  uint32_t* mask_g = (uint32_t*)w;           w += (size_t)NLBL * 256 * 4;     // 128 KB
  int* glist = (int*)w;                      w += (size_t)NLBL * GCAP * 4;    // 128 KB
  int* cnt_g = (int*)w;                      w += (size_t)NLBL * 4;
  int* counts = (int*)w;                     w += (size_t)N_ * NCHUNK * 2 * 4;        // 2 MB
  float* vals = (float*)w;                   w += (size_t)N_ * NCHUNK * CSLOT * 4;    // 16.8 MB
  float* li_arr = (float*)w;                 w += (size_t)N_ * 4;
  int* valid_arr = (int*)w;                  w += (size_t)N_ * 4;

  hipLaunchKernelGGL(prep_group_kernel, dim3(256), dim3(256), 0, stream,
                     feats, labels, inv_norm, zt, mask_g, glist, cnt_g);
  hipLaunchKernelGGL(collect_kernel, dim3(128 * NCHUNK), dim3(64), 0, stream,
                     zt, labels, mask_g, vals, counts);
  hipLaunchKernelGGL(finalize_kernel, dim3(N_ / 4), dim3(256), 0, stream,
                     feats, labels, inv_norm, glist, cnt_g, counts, vals, li_arr, valid_arr);
  hipLaunchKernelGGL(reduce_kernel, dim3(1), dim3(256), 0, stream, li_arr, valid_arr, out);
}

// Round 15
// 88.860 us; speedup vs baseline: 1.6939x; 1.6939x over previous
//
#include <hip/hip_runtime.h>
#include <cstdint>
#include <math.h>

#define N_     8192
#define D_     256
#define NLBL   128
#define TEMP_INV 14.285714285714286f
#define HARDK  10
#define THETA  0.16f
#define GCAP   256              // per-label list capacity (mean 64, max ~104)

#define NCHUNK 32
#define CHUNK  (N_ / NCHUNK)    // 256 cols per block
#define TILES  (CHUNK / 32)     // 8
#define CSLOT  16               // per-(row,chunk): slots 0-7 = kg0, 8-15 = kg1

typedef __attribute__((ext_vector_type(8)))  short bf16x8;
typedef __attribute__((ext_vector_type(16))) float f32x16;

// ---------------- Threefry-2x32, key=(0,42): exact-match validated R1-R14 ----------------
__device__ __forceinline__ uint32_t rotl32(uint32_t x, int n) {
  return (x << n) | (x >> (32 - n));
}
__device__ uint32_t tf_bits(uint32_t idx) {
  uint32_t x0 = 0u, x1 = idx;
  const uint32_t k0 = 0u, k1 = 42u;
  const uint32_t k2 = k0 ^ k1 ^ 0x1BD11BDAu;
  x0 += k0; x1 += k1;
#define TFR(r) { x0 += x1; x1 = rotl32(x1, r); x1 ^= x0; }
  TFR(13) TFR(15) TFR(26) TFR(6)
  x0 += k1; x1 += k2 + 1u;
  TFR(17) TFR(29) TFR(16) TFR(24)
  x0 += k2; x1 += k0 + 2u;
  TFR(13) TFR(15) TFR(26) TFR(6)
  x0 += k0; x1 += k1 + 3u;
  TFR(17) TFR(29) TFR(16) TFR(24)
  x0 += k1; x1 += k2 + 4u;
  TFR(13) TFR(15) TFR(26) TFR(6)
  x0 += k2; x1 += k0 + 5u;
#undef TFR
  return x0 ^ x1;
}

__device__ __forceinline__ uint32_t f2bf(float x) {  // RNE
  uint32_t b = __float_as_uint(x);
  return (b + 0x7FFFu + ((b >> 16) & 1u)) >> 16;
}

// ---------------- K1: fused prep (norm + bf16 + transpose to zt) AND group masks --------
__global__ __launch_bounds__(256) void prep_group_kernel(
    const float* __restrict__ feats, const int* __restrict__ labels,
    float* __restrict__ inv_norm, unsigned short* __restrict__ zt,
    uint32_t* __restrict__ mask_g, int* __restrict__ glist, int* __restrict__ cnt_g) {
  __shared__ uint4 tile[64][33];   // bf16 rows staged for transpose (+pad)
  __shared__ int lcnt;
  const int tid = threadIdx.x;

  if (blockIdx.x < 128) {
    const int row0 = blockIdx.x * 64;
    const int wv = tid >> 6, l = tid & 63;
#pragma unroll 4
    for (int rr = 0; rr < 16; ++rr) {
      const int rloc = wv * 16 + rr;
      const int row = row0 + rloc;
      float4 v = ((const float4*)feats)[(size_t)row * 64 + l];
      float ss = v.x * v.x + v.y * v.y + v.z * v.z + v.w * v.w;
#pragma unroll
      for (int o = 32; o; o >>= 1) ss += __shfl_xor(ss, o);
      float inv = 1.0f / fmaxf(sqrtf(ss), 1e-12f);
      if (l == 0) inv_norm[row] = inv;
      uint2 p;
      p.x = f2bf(v.x * inv) | (f2bf(v.y * inv) << 16);
      p.y = f2bf(v.z * inv) | (f2bf(v.w * inv) << 16);
      *(uint2*)((char*)&tile[0][0] + rloc * 528 + l * 8) = p;
    }
    __syncthreads();
#pragma unroll
    for (int it = 0; it < 8; ++it) {
      int c = it * 4 + (tid >> 6);
      int r = tid & 63;                  // consecutive r -> contiguous 1KB store
      ((uint4*)zt)[(size_t)c * N_ + row0 + r] = tile[r][c];
    }
  } else {
    const int b = blockIdx.x - 128;
    const int lane = tid & 63, wv = tid >> 6;
    if (tid == 0) lcnt = 0;
    __syncthreads();
    for (int it = 0; it < N_; it += 256) {
      int col = it + tid;
      bool pred = (labels[col] == b);
      unsigned long long m = __ballot(pred);
      if (lane == 0) {
        int w0 = (it + wv * 64) >> 5;
        mask_g[b * 256 + w0]     = (uint32_t)m;
        mask_g[b * 256 + w0 + 1] = (uint32_t)(m >> 32);
      }
      if (pred) {
        int p = atomicAdd(&lcnt, 1);
        if (p < GCAP) glist[b * GCAP + p] = col;
      }
    }
    __syncthreads();
    if (tid == 0) cnt_g[b] = lcnt;
  }
}

// ---------------- K2: MFMA sim — high-residency shape: 1 rowgroup/wave, 32KB dbuf ------
// Residency math: LDS 32KB -> 5 blocks/CU; grid 2048 -> 8/CU available; so ~20 waves/CU.
__device__ __forceinline__ void stage_tile(const unsigned short* zt, char (*AbK)[1024],
                                           int colT, int wid, int l, int kg) {
  // plane (kk*2+kg), rows colT..colT+31 contiguous per 32-lane half
  const char* base = (const char*)zt + ((size_t)kg * N_ + colT + (l & 31)) * 16;
#pragma unroll
  for (int q = 0; q < 4; ++q) {
    const int kk = wid * 4 + q;
    __builtin_amdgcn_global_load_lds(
        (const __attribute__((address_space(1))) void*)(base + (size_t)kk * (2 * N_ * 16)),
        (__attribute__((address_space(3))) void*)(&AbK[kk][0]), 16, 0, 0);
  }
}

#define INS8(H0,H1,H2,H3,H4,H5,H6,H7,POS,C) \
  { H0 = (POS==0)?(C):H0; H1 = (POS==1)?(C):H1; H2 = (POS==2)?(C):H2; H3 = (POS==3)?(C):H3; \
    H4 = (POS==4)?(C):H4; H5 = (POS==5)?(C):H5; H6 = (POS==6)?(C):H6; H7 = (POS==7)?(C):H7; \
    ++POS; }

__global__ __launch_bounds__(256) void collect_kernel(const unsigned short* __restrict__ zt,
                                                      const int* __restrict__ labels,
                                                      const uint32_t* __restrict__ mask_g,
                                                      float* __restrict__ vals,
                                                      int* __restrict__ counts) {
  __shared__ char Ab[2][16][1024];        // double buffer, 32 KB

  const int tid = threadIdx.x;
  const int l = tid & 63, wid = tid >> 6;
  const int kg = l >> 5;
  const int bx = blockIdx.x;
  const int rc = bx & 63, cc = bx >> 6;   // 64 row-chunks x 32 col-chunks = 2048 blocks
  const int row0 = rc * 128;
  const int col0 = cc * CHUNK;
  const int rowW = row0 + wid * 32 + (l & 31);
  const int lab = labels[rowW];

  // all 8 tile-masks preloaded to registers
  uint32_t mW[TILES];
  {
    const uint4* mm = (const uint4*)(mask_g + lab * 256 + (col0 >> 5));
    uint4 m0 = mm[0], m1 = mm[1];
    mW[0]=m0.x; mW[1]=m0.y; mW[2]=m0.z; mW[3]=m0.w;
    mW[4]=m1.x; mW[5]=m1.y; mW[6]=m1.z; mW[7]=m1.w;
  }

  // B fragments from K-major planes: contiguous 512B per 32-lane half (64 VGPR)
  bf16x8 bf[16];
  {
    const uint4* ztq = (const uint4*)zt;
#pragma unroll
    for (int kk = 0; kk < 16; ++kk)
      bf[kk] = *(const bf16x8*)&ztq[(size_t)(kk * 2 + kg) * N_ + rowW];
  }

  // hit slots in registers (static select-chain)
  float h0=0,h1=0,h2=0,h3=0,h4=0,h5=0,h6=0,h7=0;
  int pos = 0;
  float* vb = vals + ((size_t)rowW * NCHUNK + cc) * CSLOT + kg * 8;

  stage_tile(zt, Ab[0], col0, wid, l, kg);
  __syncthreads();

  int buf = 0;
#pragma unroll
  for (int t = 0; t < TILES; ++t) {
    if (t + 1 < TILES) stage_tile(zt, Ab[buf ^ 1], col0 + (t + 1) * 32, wid, l, kg);

    f32x16 acc;
#pragma unroll
    for (int r = 0; r < 16; ++r) acc[r] = 0.f;
    __builtin_amdgcn_s_setprio(1);
#pragma unroll
    for (int kk = 0; kk < 16; ++kk) {
      bf16x8 a = *(const bf16x8*)&Ab[buf][kk][l * 16];
      acc = __builtin_amdgcn_mfma_f32_32x32x16_bf16(a, bf[kk], acc, 0, 0, 0);
    }
    __builtin_amdgcn_s_setprio(0);

    // scan into register slots (__any-gated; fires ~15%/step for 1 rowgroup)
    const uint32_t wsh = mW[t] >> (kg * 4);
#pragma unroll
    for (int r = 0; r < 16; ++r) {
      const int cpos = (r & 3) + 8 * (r >> 2);
      bool hit = ((((wsh >> cpos) & 1u) == 0u) && (acc[r] > THETA));
      if (__any(hit)) {
        if (hit) { INS8(h0,h1,h2,h3,h4,h5,h6,h7, pos, acc[r]); }
      }
    }
    __syncthreads();   // stage(t+1) landed (implicit vmcnt(0)) + all reads of buf done
    buf ^= 1;
  }

  // ---- flush: registers -> global (coalesced float4 stores) ----
  {
    float4 a0 = {h0, h1, h2, h3};
    float4 a1 = {h4, h5, h6, h7};
    *(float4*)(vb)     = a0;
    *(float4*)(vb + 4) = a1;
    counts[(rowW * NCHUNK + cc) * 2 + kg] = pos;
  }
}

// ---------------- K3: finalize (1 wave/row): pos pick + top-10 of collected + loss ----------------
__global__ __launch_bounds__(256) void finalize_kernel(
    const float* __restrict__ feats, const int* __restrict__ labels,
    const float* __restrict__ inv_norm,
    const int* __restrict__ glist, const int* __restrict__ cnt_g,
    const int* __restrict__ counts, const float* __restrict__ vals,
    float* __restrict__ li, int* __restrict__ valid) {
  const int row = blockIdx.x * 4 + (threadIdx.x >> 6);
  const int lane = threadIdx.x & 63;
  const int lab = labels[row];
  const int gc = cnt_g[lab];
  const int gn = gc < GCAP ? gc : GCAP;
  const float4* feats4 = (const float4*)feats;

  // --- positive pick: threefry argmax over same-label (excl self) ---
  uint32_t bk = 0u; int bj = -1;
  for (int e = lane; e < gn; e += 64) {
    int j = glist[lab * GCAP + e];
    if (j != row) {
      uint32_t key = tf_bits((uint32_t)row * (uint32_t)N_ + (uint32_t)j) >> 9;
      if (bj < 0 || key > bk || (key == bk && j < bj)) { bk = key; bj = j; }
    }
  }
#pragma unroll
  for (int o = 32; o; o >>= 1) {
    uint32_t ok = __shfl_xor(bk, o);
    int oj = __shfl_xor(bj, o);
    if (oj >= 0 && (bj < 0 || ok > bk || (ok == bk && oj < bj))) { bk = ok; bj = oj; }
  }

  // --- exact fp32 positive cosine ---
  float pc = 0.f;
  if (bj >= 0) {
    float4 a = feats4[(size_t)row * 64 + lane];
    float4 b = feats4[(size_t)bj * 64 + lane];
    float p = a.x * b.x + a.y * b.y + a.z * b.z + a.w * b.w;
#pragma unroll
    for (int o = 32; o; o >>= 1) p += __shfl_xor(p, o);
    pc = p * inv_norm[row] * inv_norm[bj];
  }

  // --- load collected: 32 cells x 16 slots = 512, 8 per lane (coalesced) ---
  float vv[8];
  int ovf = 0;
#pragma unroll
  for (int q = 0; q < 8; ++q) {
    int s = lane + 64 * q;           // slot id 0..511
    int cell = s >> 4, wi = s & 15;  // chunk cell 0..31; slot 0-7=kg0, 8-15=kg1
    int c0 = counts[(row * NCHUNK + cell) * 2 + 0];
    int c1 = counts[(row * NCHUNK + cell) * 2 + 1];
    ovf |= ((c0 > 8) || (c1 > 8)) ? 1 : 0;
    float val = vals[(size_t)row * (NCHUNK * CSLOT) + s];
    bool live = (wi < 8) ? (wi < c0) : ((wi - 8) < c1);
    vv[q] = live ? val : -INFINITY;
  }

  float num = expf(pc * TEMP_INV);
  float den = num;
  int got = 0;
#pragma unroll 1
  for (int it = 0; it < HARDK; ++it) {
    float lm = fmaxf(fmaxf(fmaxf(vv[0], vv[1]), fmaxf(vv[2], vv[3])),
                     fmaxf(fmaxf(vv[4], vv[5]), fmaxf(vv[6], vv[7])));
    float wm = lm;
#pragma unroll
    for (int o = 32; o; o >>= 1) wm = fmaxf(wm, __shfl_xor(wm, o));
    if (wm < -1e37f) break;
    den += expf(wm * TEMP_INV);
    ++got;
    unsigned long long b = __ballot(lm == wm);
    int fl = __ffsll((long long)b) - 1;
    if (lane == fl) {
      if      (vv[0] == wm) vv[0] = -INFINITY;
      else if (vv[1] == wm) vv[1] = -INFINITY;
      else if (vv[2] == wm) vv[2] = -INFINITY;
      else if (vv[3] == wm) vv[3] = -INFINITY;
      else if (vv[4] == wm) vv[4] = -INFINITY;
      else if (vv[5] == wm) vv[5] = -INFINITY;
      else if (vv[6] == wm) vv[6] = -INFINITY;
      else                  vv[7] = -INFINITY;
    }
  }

  const int ndiff = N_ - gc;
  const bool vld = (bj >= 0) && (ndiff > 0);
  const int want = ndiff < HARDK ? ndiff : HARDK;

  // --- exact cooperative fallback (P ~ 1e-9/cell; guarantees exactness) ---
  if (vld && (__any(ovf) || got < want)) {
    float tk[HARDK];
#pragma unroll
    for (int k = 0; k < HARDK; ++k) tk[k] = -INFINITY;
    const float invr = inv_norm[row];
    const float4 a = feats4[(size_t)row * 64 + lane];   // whole row: 64 lanes x float4
#pragma unroll 1
    for (int j = 0; j < N_; ++j) {
      if (j == row || labels[j] == lab) continue;       // wave-uniform branch
      float4 b = feats4[(size_t)j * 64 + lane];
      float p = a.x * b.x + a.y * b.y + a.z * b.z + a.w * b.w;
#pragma unroll
      for (int o = 32; o; o >>= 1) p += __shfl_xor(p, o);
      float c = p * invr * inv_norm[j];                 // wave-uniform value
      if (c > tk[0]) {
        tk[0] = c;
#pragma unroll
        for (int q = 0; q < HARDK - 1; ++q)
          if (tk[q] > tk[q + 1]) { float tmp = tk[q]; tk[q] = tk[q + 1]; tk[q + 1] = tmp; }
      }
    }
    den = num;
#pragma unroll
    for (int k = 0; k < HARDK; ++k)
      if (tk[k] > -1e37f) den += expf(tk[k] * TEMP_INV);
  }

  float L = 0.f;
  if (vld) L = -logf(fmaxf(num / fmaxf(den, 1e-8f), 1e-8f));
  if (lane == 0) {
    li[row] = L;
    valid[row] = vld ? 1 : 0;
  }
}

// ---------------- K4: final mean ----------------
__global__ __launch_bounds__(256) void reduce_kernel(const float* __restrict__ li,
                                                     const int* __restrict__ valid,
                                                     float* __restrict__ out) {
  __shared__ float ssum[4];
  __shared__ int scnt[4];
  float s = 0.f; int c = 0;
  for (int i = threadIdx.x; i < N_; i += 256) { s += li[i]; c += valid[i]; }
#pragma unroll
  for (int o = 32; o; o >>= 1) { s += __shfl_down(s, o); c += __shfl_down(c, o); }
  if ((threadIdx.x & 63) == 0) { ssum[threadIdx.x >> 6] = s; scnt[threadIdx.x >> 6] = c; }
  __syncthreads();
  if (threadIdx.x == 0) {
    float S = 0.f; int C = 0;
    for (int w = 0; w < 4; ++w) { S += ssum[w]; C += scnt[w]; }
    out[0] = S / (float)(C > 0 ? C : 1);
  }
}

extern "C" void kernel_launch(void* const* d_in, const int* in_sizes, int n_in,
                              void* d_out, int out_size, void* d_ws, size_t ws_size,
                              hipStream_t stream) {
  const float* feats  = (const float*)d_in[0];
  const int*   labels = (const int*)d_in[1];
  float* out = (float*)d_out;

  char* w = (char*)d_ws;
  unsigned short* zt  = (unsigned short*)w;  w += (size_t)N_ * D_ * 2;        // 4 MB (K-major)
  float* inv_norm = (float*)w;               w += (size_t)N_ * 4;
  uint32_t* mask_g = (uint32_t*)w;           w += (size_t)NLBL * 256 * 4;     // 128 KB
  int* glist = (int*)w;                      w += (size_t)NLBL * GCAP * 4;    // 128 KB
  int* cnt_g = (int*)w;                      w += (size_t)NLBL * 4;
  int* counts = (int*)w;                     w += (size_t)N_ * NCHUNK * 2 * 4;        // 2 MB
  float* vals = (float*)w;                   w += (size_t)N_ * NCHUNK * CSLOT * 4;    // 16.8 MB
  float* li_arr = (float*)w;                 w += (size_t)N_ * 4;
  int* valid_arr = (int*)w;                  w += (size_t)N_ * 4;

  hipLaunchKernelGGL(prep_group_kernel, dim3(256), dim3(256), 0, stream,
                     feats, labels, inv_norm, zt, mask_g, glist, cnt_g);
  hipLaunchKernelGGL(collect_kernel, dim3(64 * NCHUNK), dim3(256), 0, stream,
                     zt, labels, mask_g, vals, counts);
  hipLaunchKernelGGL(finalize_kernel, dim3(N_ / 4), dim3(256), 0, stream,
                     feats, labels, inv_norm, glist, cnt_g, counts, vals, li_arr, valid_arr);
  hipLaunchKernelGGL(reduce_kernel, dim3(1), dim3(256), 0, stream, li_arr, valid_arr, out);
}

// Round 16
// 88.468 us; speedup vs baseline: 1.7014x; 1.0044x over previous
//
#include <hip/hip_runtime.h>
#include <cstdint>
#include <math.h>

#define N_     8192
#define D_     256
#define NLBL   128
#define TEMP_INV 14.285714285714286f
#define HARDK  10
#define THETA  0.16f
#define GCAP   256              // per-label list capacity (mean 64, max ~104)

#define NCHUNK 32
#define CHUNK  (N_ / NCHUNK)    // 256 cols per block
#define TILES  (CHUNK / 32)     // 8
#define CSLOT  16               // per-(row,chunk): slots 0-7 = kg0, 8-15 = kg1

typedef __attribute__((ext_vector_type(8)))  short bf16x8;
typedef __attribute__((ext_vector_type(16))) float f32x16;

// ---------------- Threefry-2x32, key=(0,42): exact-match validated R1-R15 ----------------
__device__ __forceinline__ uint32_t rotl32(uint32_t x, int n) {
  return (x << n) | (x >> (32 - n));
}
__device__ uint32_t tf_bits(uint32_t idx) {
  uint32_t x0 = 0u, x1 = idx;
  const uint32_t k0 = 0u, k1 = 42u;
  const uint32_t k2 = k0 ^ k1 ^ 0x1BD11BDAu;
  x0 += k0; x1 += k1;
#define TFR(r) { x0 += x1; x1 = rotl32(x1, r); x1 ^= x0; }
  TFR(13) TFR(15) TFR(26) TFR(6)
  x0 += k1; x1 += k2 + 1u;
  TFR(17) TFR(29) TFR(16) TFR(24)
  x0 += k2; x1 += k0 + 2u;
  TFR(13) TFR(15) TFR(26) TFR(6)
  x0 += k0; x1 += k1 + 3u;
  TFR(17) TFR(29) TFR(16) TFR(24)
  x0 += k1; x1 += k2 + 4u;
  TFR(13) TFR(15) TFR(26) TFR(6)
  x0 += k2; x1 += k0 + 5u;
#undef TFR
  return x0 ^ x1;
}

__device__ __forceinline__ uint32_t f2bf(float x) {  // RNE
  uint32_t b = __float_as_uint(x);
  return (b + 0x7FFFu + ((b >> 16) & 1u)) >> 16;
}

// ---------------- K1: fused prep (512 blocks x 16 rows) + group masks (128 blocks) -----
__global__ __launch_bounds__(256) void prep_group_kernel(
    const float* __restrict__ feats, const int* __restrict__ labels,
    float* __restrict__ inv_norm, unsigned short* __restrict__ zt,
    uint32_t* __restrict__ mask_g, int* __restrict__ glist, int* __restrict__ cnt_g) {
  __shared__ uint4 tile[16][33];   // bf16 rows staged for transpose (+pad)
  __shared__ int lcnt;
  const int tid = threadIdx.x;

  if (blockIdx.x < 512) {
    const int row0 = blockIdx.x * 16;
    const int wv = tid >> 6, l = tid & 63;
#pragma unroll
    for (int rr = 0; rr < 4; ++rr) {
      const int rloc = wv * 4 + rr;
      const int row = row0 + rloc;
      float4 v = ((const float4*)feats)[(size_t)row * 64 + l];
      float ss = v.x * v.x + v.y * v.y + v.z * v.z + v.w * v.w;
#pragma unroll
      for (int o = 32; o; o >>= 1) ss += __shfl_xor(ss, o);
      float inv = 1.0f / fmaxf(sqrtf(ss), 1e-12f);
      if (l == 0) inv_norm[row] = inv;
      uint2 p;
      p.x = f2bf(v.x * inv) | (f2bf(v.y * inv) << 16);
      p.y = f2bf(v.z * inv) | (f2bf(v.w * inv) << 16);
      *(uint2*)((char*)&tile[0][0] + rloc * 528 + l * 8) = p;
    }
    __syncthreads();
#pragma unroll
    for (int it = 0; it < 2; ++it) {
      int idx = it * 256 + tid;          // 0..511
      int c = idx >> 4, r = idx & 15;    // consecutive tid -> consecutive r (256B seg)
      ((uint4*)zt)[(size_t)c * N_ + row0 + r] = tile[r][c];
    }
  } else {
    const int b = blockIdx.x - 512;
    const int lane = tid & 63, wv = tid >> 6;
    if (tid == 0) lcnt = 0;
    __syncthreads();
    for (int it = 0; it < N_; it += 256) {
      int col = it + tid;
      bool pred = (labels[col] == b);
      unsigned long long m = __ballot(pred);
      if (lane == 0) {
        int w0 = (it + wv * 64) >> 5;
        mask_g[b * 256 + w0]     = (uint32_t)m;
        mask_g[b * 256 + w0 + 1] = (uint32_t)(m >> 32);
      }
      if (pred) {
        int p = atomicAdd(&lcnt, 1);
        if (p < GCAP) glist[b * GCAP + p] = col;
      }
    }
    __syncthreads();
    if (tid == 0) cnt_g[b] = lcnt;
  }
}

// ---------------- K2: MFMA sim — 8-wave blocks, 256 rows/block, 32KB dbuf --------------
// Residency: LDS 32KB -> 5 blocks/CU; grid 1024 -> 4/CU -> up to 32 waves/CU.
// Staging traffic halves vs R15 (32 row-blocks per col-chunk instead of 64).
__device__ __forceinline__ void stage_tile(const unsigned short* zt, char (*AbK)[1024],
                                           int colT, int wid, int l, int kg) {
  // plane (kk*2+kg), rows colT..colT+31 contiguous per 32-lane half
  const char* base = (const char*)zt + ((size_t)kg * N_ + colT + (l & 31)) * 16;
#pragma unroll
  for (int q = 0; q < 2; ++q) {
    const int kk = wid * 2 + q;
    __builtin_amdgcn_global_load_lds(
        (const __attribute__((address_space(1))) void*)(base + (size_t)kk * (2 * N_ * 16)),
        (__attribute__((address_space(3))) void*)(&AbK[kk][0]), 16, 0, 0);
  }
}

#define INS8(H0,H1,H2,H3,H4,H5,H6,H7,POS,C) \
  { H0 = (POS==0)?(C):H0; H1 = (POS==1)?(C):H1; H2 = (POS==2)?(C):H2; H3 = (POS==3)?(C):H3; \
    H4 = (POS==4)?(C):H4; H5 = (POS==5)?(C):H5; H6 = (POS==6)?(C):H6; H7 = (POS==7)?(C):H7; \
    ++POS; }

__global__ __launch_bounds__(512) void collect_kernel(const unsigned short* __restrict__ zt,
                                                      const int* __restrict__ labels,
                                                      const uint32_t* __restrict__ mask_g,
                                                      float* __restrict__ vals,
                                                      int* __restrict__ counts) {
  __shared__ char Ab[2][16][1024];        // double buffer, 32 KB (shared by 8 waves)

  const int tid = threadIdx.x;
  const int l = tid & 63, wid = tid >> 6;  // wid 0..7
  const int kg = l >> 5;
  const int bx = blockIdx.x;
  const int rc = bx & 31, cc = bx >> 5;    // 32 row-chunks x 32 col-chunks = 1024 blocks
  const int row0 = rc * 256;
  const int col0 = cc * CHUNK;
  const int rowW = row0 + wid * 32 + (l & 31);
  const int lab = labels[rowW];

  // all 8 tile-masks preloaded to registers
  uint32_t mW[TILES];
  {
    const uint4* mm = (const uint4*)(mask_g + lab * 256 + (col0 >> 5));
    uint4 m0 = mm[0], m1 = mm[1];
    mW[0]=m0.x; mW[1]=m0.y; mW[2]=m0.z; mW[3]=m0.w;
    mW[4]=m1.x; mW[5]=m1.y; mW[6]=m1.z; mW[7]=m1.w;
  }

  // B fragments from K-major planes: contiguous 512B per 32-lane half (AGPR-parked)
  bf16x8 bf[16];
  {
    const uint4* ztq = (const uint4*)zt;
#pragma unroll
    for (int kk = 0; kk < 16; ++kk)
      bf[kk] = *(const bf16x8*)&ztq[(size_t)(kk * 2 + kg) * N_ + rowW];
  }

  // hit slots in registers (static select-chain)
  float h0=0,h1=0,h2=0,h3=0,h4=0,h5=0,h6=0,h7=0;
  int pos = 0;
  float* vb = vals + ((size_t)rowW * NCHUNK + cc) * CSLOT + kg * 8;

  stage_tile(zt, Ab[0], col0, wid, l, kg);
  __syncthreads();

  int buf = 0;
#pragma unroll
  for (int t = 0; t < TILES; ++t) {
    if (t + 1 < TILES) stage_tile(zt, Ab[buf ^ 1], col0 + (t + 1) * 32, wid, l, kg);

    f32x16 acc;
#pragma unroll
    for (int r = 0; r < 16; ++r) acc[r] = 0.f;
    __builtin_amdgcn_s_setprio(1);
#pragma unroll
    for (int kk = 0; kk < 16; ++kk) {
      bf16x8 a = *(const bf16x8*)&Ab[buf][kk][l * 16];
      acc = __builtin_amdgcn_mfma_f32_32x32x16_bf16(a, bf[kk], acc, 0, 0, 0);
    }
    __builtin_amdgcn_s_setprio(0);

    // scan into register slots (__any-gated)
    const uint32_t wsh = mW[t] >> (kg * 4);
#pragma unroll
    for (int r = 0; r < 16; ++r) {
      const int cpos = (r & 3) + 8 * (r >> 2);
      bool hit = ((((wsh >> cpos) & 1u) == 0u) && (acc[r] > THETA));
      if (__any(hit)) {
        if (hit) { INS8(h0,h1,h2,h3,h4,h5,h6,h7, pos, acc[r]); }
      }
    }
    __syncthreads();   // stage(t+1) landed (implicit vmcnt(0)) + all reads of buf done
    buf ^= 1;
  }

  // ---- flush: registers -> global (coalesced float4 stores) ----
  {
    float4 a0 = {h0, h1, h2, h3};
    float4 a1 = {h4, h5, h6, h7};
    *(float4*)(vb)     = a0;
    *(float4*)(vb + 4) = a1;
    counts[(rowW * NCHUNK + cc) * 2 + kg] = pos;
  }
}

// ---------------- K3: finalize (1 wave/row): pos pick + top-10 of collected + loss ----------------
__global__ __launch_bounds__(256) void finalize_kernel(
    const float* __restrict__ feats, const int* __restrict__ labels,
    const float* __restrict__ inv_norm,
    const int* __restrict__ glist, const int* __restrict__ cnt_g,
    const int* __restrict__ counts, const float* __restrict__ vals,
    float* __restrict__ li, int* __restrict__ valid) {
  const int row = blockIdx.x * 4 + (threadIdx.x >> 6);
  const int lane = threadIdx.x & 63;
  const int lab = labels[row];
  const int gc = cnt_g[lab];
  const int gn = gc < GCAP ? gc : GCAP;
  const float4* feats4 = (const float4*)feats;

  // --- positive pick: threefry argmax over same-label (excl self) ---
  uint32_t bk = 0u; int bj = -1;
  for (int e = lane; e < gn; e += 64) {
    int j = glist[lab * GCAP + e];
    if (j != row) {
      uint32_t key = tf_bits((uint32_t)row * (uint32_t)N_ + (uint32_t)j) >> 9;
      if (bj < 0 || key > bk || (key == bk && j < bj)) { bk = key; bj = j; }
    }
  }
#pragma unroll
  for (int o = 32; o; o >>= 1) {
    uint32_t ok = __shfl_xor(bk, o);
    int oj = __shfl_xor(bj, o);
    if (oj >= 0 && (bj < 0 || ok > bk || (ok == bk && oj < bj))) { bk = ok; bj = oj; }
  }

  // --- exact fp32 positive cosine ---
  float pc = 0.f;
  if (bj >= 0) {
    float4 a = feats4[(size_t)row * 64 + lane];
    float4 b = feats4[(size_t)bj * 64 + lane];
    float p = a.x * b.x + a.y * b.y + a.z * b.z + a.w * b.w;
#pragma unroll
    for (int o = 32; o; o >>= 1) p += __shfl_xor(p, o);
    pc = p * inv_norm[row] * inv_norm[bj];
  }

  // --- load collected: 32 cells x 16 slots = 512, 8 per lane (coalesced) ---
  float vv[8];
  int ovf = 0;
#pragma unroll
  for (int q = 0; q < 8; ++q) {
    int s = lane + 64 * q;           // slot id 0..511
    int cell = s >> 4, wi = s & 15;  // chunk cell 0..31; slot 0-7=kg0, 8-15=kg1
    int c0 = counts[(row * NCHUNK + cell) * 2 + 0];
    int c1 = counts[(row * NCHUNK + cell) * 2 + 1];
    ovf |= ((c0 > 8) || (c1 > 8)) ? 1 : 0;
    float val = vals[(size_t)row * (NCHUNK * CSLOT) + s];
    bool live = (wi < 8) ? (wi < c0) : ((wi - 8) < c1);
    vv[q] = live ? val : -INFINITY;
  }

  float num = expf(pc * TEMP_INV);
  float den = num;
  int got = 0;
#pragma unroll 1
  for (int it = 0; it < HARDK; ++it) {
    float lm = fmaxf(fmaxf(fmaxf(vv[0], vv[1]), fmaxf(vv[2], vv[3])),
                     fmaxf(fmaxf(vv[4], vv[5]), fmaxf(vv[6], vv[7])));
    float wm = lm;
#pragma unroll
    for (int o = 32; o; o >>= 1) wm = fmaxf(wm, __shfl_xor(wm, o));
    if (wm < -1e37f) break;
    den += expf(wm * TEMP_INV);
    ++got;
    unsigned long long b = __ballot(lm == wm);
    int fl = __ffsll((long long)b) - 1;
    if (lane == fl) {
      if      (vv[0] == wm) vv[0] = -INFINITY;
      else if (vv[1] == wm) vv[1] = -INFINITY;
      else if (vv[2] == wm) vv[2] = -INFINITY;
      else if (vv[3] == wm) vv[3] = -INFINITY;
      else if (vv[4] == wm) vv[4] = -INFINITY;
      else if (vv[5] == wm) vv[5] = -INFINITY;
      else if (vv[6] == wm) vv[6] = -INFINITY;
      else                  vv[7] = -INFINITY;
    }
  }

  const int ndiff = N_ - gc;
  const bool vld = (bj >= 0) && (ndiff > 0);
  const int want = ndiff < HARDK ? ndiff : HARDK;

  // --- exact cooperative fallback (P ~ 1e-9/cell; guarantees exactness) ---
  if (vld && (__any(ovf) || got < want)) {
    float tk[HARDK];
#pragma unroll
    for (int k = 0; k < HARDK; ++k) tk[k] = -INFINITY;
    const float invr = inv_norm[row];
    const float4 a = feats4[(size_t)row * 64 + lane];   // whole row: 64 lanes x float4
#pragma unroll 1
    for (int j = 0; j < N_; ++j) {
      if (j == row || labels[j] == lab) continue;       // wave-uniform branch
      float4 b = feats4[(size_t)j * 64 + lane];
      float p = a.x * b.x + a.y * b.y + a.z * b.z + a.w * b.w;
#pragma unroll
      for (int o = 32; o; o >>= 1) p += __shfl_xor(p, o);
      float c = p * invr * inv_norm[j];                 // wave-uniform value
      if (c > tk[0]) {
        tk[0] = c;
#pragma unroll
        for (int q = 0; q < HARDK - 1; ++q)
          if (tk[q] > tk[q + 1]) { float tmp = tk[q]; tk[q] = tk[q + 1]; tk[q + 1] = tmp; }
      }
    }
    den = num;
#pragma unroll
    for (int k = 0; k < HARDK; ++k)
      if (tk[k] > -1e37f) den += expf(tk[k] * TEMP_INV);
  }

  float L = 0.f;
  if (vld) L = -logf(fmaxf(num / fmaxf(den, 1e-8f), 1e-8f));
  if (lane == 0) {
    li[row] = L;
    valid[row] = vld ? 1 : 0;
  }
}

// ---------------- K4: final mean ----------------
__global__ __launch_bounds__(256) void reduce_kernel(const float* __restrict__ li,
                                                     const int* __restrict__ valid,
                                                     float* __restrict__ out) {
  __shared__ float ssum[4];
  __shared__ int scnt[4];
  float s = 0.f; int c = 0;
  for (int i = threadIdx.x; i < N_; i += 256) { s += li[i]; c += valid[i]; }
#pragma unroll
  for (int o = 32; o; o >>= 1) { s += __shfl_down(s, o); c += __shfl_down(c, o); }
  if ((threadIdx.x & 63) == 0) { ssum[threadIdx.x >> 6] = s; scnt[threadIdx.x >> 6] = c; }
  __syncthreads();
  if (threadIdx.x == 0) {
    float S = 0.f; int C = 0;
    for (int w = 0; w < 4; ++w) { S += ssum[w]; C += scnt[w]; }
    out[0] = S / (float)(C > 0 ? C : 1);
  }
}

extern "C" void kernel_launch(void* const* d_in, const int* in_sizes, int n_in,
                              void* d_out, int out_size, void* d_ws, size_t ws_size,
                              hipStream_t stream) {
  const float* feats  = (const float*)d_in[0];
  const int*   labels = (const int*)d_in[1];
  float* out = (float*)d_out;

  char* w = (char*)d_ws;
  unsigned short* zt  = (unsigned short*)w;  w += (size_t)N_ * D_ * 2;        // 4 MB (K-major)
  float* inv_norm = (float*)w;               w += (size_t)N_ * 4;
  uint32_t* mask_g = (uint32_t*)w;           w += (size_t)NLBL * 256 * 4;     // 128 KB
  int* glist = (int*)w;                      w += (size_t)NLBL * GCAP * 4;    // 128 KB
  int* cnt_g = (int*)w;                      w += (size_t)NLBL * 4;
  int* counts = (int*)w;                     w += (size_t)N_ * NCHUNK * 2 * 4;        // 2 MB
  float* vals = (float*)w;                   w += (size_t)N_ * NCHUNK * CSLOT * 4;    // 16.8 MB
  float* li_arr = (float*)w;                 w += (size_t)N_ * 4;
  int* valid_arr = (int*)w;                  w += (size_t)N_ * 4;

  hipLaunchKernelGGL(prep_group_kernel, dim3(640), dim3(256), 0, stream,
                     feats, labels, inv_norm, zt, mask_g, glist, cnt_g);
  hipLaunchKernelGGL(collect_kernel, dim3(32 * NCHUNK), dim3(512), 0, stream,
                     zt, labels, mask_g, vals, counts);
  hipLaunchKernelGGL(finalize_kernel, dim3(N_ / 4), dim3(256), 0, stream,
                     feats, labels, inv_norm, glist, cnt_g, counts, vals, li_arr, valid_arr);
  hipLaunchKernelGGL(reduce_kernel, dim3(1), dim3(256), 0, stream, li_arr, valid_arr, out);
}